// Round 3
// baseline (368.062 us; speedup 1.0000x reference)
//
#include <hip/hip_runtime.h>

#define GLOBAL_AS __attribute__((address_space(1)))
#define LDS_AS    __attribute__((address_space(3)))

typedef __bf16 bf16x8 __attribute__((ext_vector_type(8)));
typedef float  f32x4  __attribute__((ext_vector_type(4)));

// Problem dims (fixed by the reference)
constexpr int SRC_STRIDE = 8192 * 80;         // floats per batch row: 655360
constexpr int TOUT       = 2728;              // output time steps
constexpr long OUT_ELEMS = (long)TOUT * 16 * 1024;  // 44695552
constexpr int SRC_ELEMS  = 32 * SRC_STRIDE;   // 20971520
constexpr int W_ELEMS    = 1024 * 640;        // 655360
constexpr int MBLK       = 341;               // 87296 / 256 (exact)
constexpr int SLOT       = 16384;             // bf16 elems per LDS slot (A 8192 + B 8192)

__device__ __forceinline__ unsigned short f2bf(float f) {
    union { float f; unsigned u; } a; a.f = f;
    unsigned r = a.u + 0x7FFF + ((a.u >> 16) & 1);   // round-to-nearest-even
    return (unsigned short)(r >> 16);
}

// fp32 -> bf16 conversion, 4 elements/thread
__global__ void cvt_kernel(const float* __restrict__ in, unsigned short* __restrict__ out, int n4) {
    int i = blockIdx.x * blockDim.x + threadIdx.x;
    if (i >= n4) return;
    float4 v = ((const float4*)in)[i];
    ushort4 o;
    o.x = f2bf(v.x); o.y = f2bf(v.y); o.z = f2bf(v.z); o.w = f2bf(v.w);
    ((ushort4*)out)[i] = o;
}

// out_lengths = src_lengths // 3 - 2, written as fp32 after the main output
__global__ void lengths_kernel(const int* __restrict__ len, float* __restrict__ out) {
    int i = threadIdx.x;
    if (i < 32) out[OUT_ELEMS + i] = (float)(len[i] / 3 - 2);
}

// ---- macros for the pipelined GEMM ----
#define GLD(gp, lp) __builtin_amdgcn_global_load_lds((const GLOBAL_AS void*)(gp), \
                                                     (LDS_AS void*)(lp), 16, 0, 0)

// stage one K-tile (4 x global_load_lds, 16B/lane) into slot tile_&3
#define STAGE_T(tile_) do {                                    \
    const int kg_ = (tile_) * 32;                              \
    const int so_ = ((tile_) & 3) * SLOT;                      \
    GLD(A  + (aG[0] + kg_), lds + so_ + aD0);                  \
    GLD(A  + (aG[1] + kg_), lds + so_ + aD1);                  \
    GLD(Wb + (bG[0] + kg_), lds + so_ + bD0);                  \
    GLD(Wb + (bG[1] + kg_), lds + so_ + bD1);                  \
} while (0)

// 8 reads: all B frags + A frags 0-3 of set P
#define READ_B4_A4(P, sa_, sb_)                                                  \
    asm volatile("ds_read_b128 %0, %1 offset:0"    : "=v"(b##P##0) : "v"(sb_));  \
    asm volatile("ds_read_b128 %0, %1 offset:1024" : "=v"(b##P##1) : "v"(sb_));  \
    asm volatile("ds_read_b128 %0, %1 offset:2048" : "=v"(b##P##2) : "v"(sb_));  \
    asm volatile("ds_read_b128 %0, %1 offset:3072" : "=v"(b##P##3) : "v"(sb_));  \
    asm volatile("ds_read_b128 %0, %1 offset:0"    : "=v"(a##P##0) : "v"(sa_));  \
    asm volatile("ds_read_b128 %0, %1 offset:1024" : "=v"(a##P##1) : "v"(sa_));  \
    asm volatile("ds_read_b128 %0, %1 offset:2048" : "=v"(a##P##2) : "v"(sa_));  \
    asm volatile("ds_read_b128 %0, %1 offset:3072" : "=v"(a##P##3) : "v"(sa_));

// 4 reads: A frags 4-7 of set P
#define READ_A4HI(P, sa_)                                                        \
    asm volatile("ds_read_b128 %0, %1 offset:4096" : "=v"(a##P##4) : "v"(sa_));  \
    asm volatile("ds_read_b128 %0, %1 offset:5120" : "=v"(a##P##5) : "v"(sa_));  \
    asm volatile("ds_read_b128 %0, %1 offset:6144" : "=v"(a##P##6) : "v"(sa_));  \
    asm volatile("ds_read_b128 %0, %1 offset:7168" : "=v"(a##P##7) : "v"(sa_));

#define MR4(a_, P, i_)                                                                  \
    acc[i_][0] = __builtin_amdgcn_mfma_f32_16x16x32_bf16(a_, b##P##0, acc[i_][0],0,0,0); \
    acc[i_][1] = __builtin_amdgcn_mfma_f32_16x16x32_bf16(a_, b##P##1, acc[i_][1],0,0,0); \
    acc[i_][2] = __builtin_amdgcn_mfma_f32_16x16x32_bf16(a_, b##P##2, acc[i_][2],0,0,0); \
    acc[i_][3] = __builtin_amdgcn_mfma_f32_16x16x32_bf16(a_, b##P##3, acc[i_][3],0,0,0);

#define MFMA_LO(P) MR4(a##P##0, P, 0) MR4(a##P##1, P, 1) MR4(a##P##2, P, 2) MR4(a##P##3, P, 3)
#define MFMA_HI(P) MR4(a##P##4, P, 4) MR4(a##P##5, P, 5) MR4(a##P##6, P, 6) MR4(a##P##7, P, 7)

// one K-tile: consume set CUR (tile t_), load set NXT (tile t_+1), stage tile t_+3
#define TILE(CUR, NXT, t_, do_stage_) do {                                       \
    if (do_stage_) STAGE_T((t_) + 3);                                            \
    const unsigned soff_ = (unsigned)((((t_) + 1) & 3) << 15);                   \
    const unsigned sa_ = adrA0 + soff_;                                          \
    const unsigned sb_ = adrB0 + soff_;                                          \
    READ_B4_A4(NXT, sa_, sb_)                                                    \
    asm volatile("s_waitcnt lgkmcnt(8)" ::: "memory");                           \
    __builtin_amdgcn_sched_barrier(0);                                           \
    __builtin_amdgcn_s_setprio(1);                                               \
    MFMA_LO(CUR)                                                                 \
    __builtin_amdgcn_s_setprio(0);                                               \
    READ_A4HI(NXT, sa_)                                                          \
    __builtin_amdgcn_s_setprio(1);                                               \
    MFMA_HI(CUR)                                                                 \
    __builtin_amdgcn_s_setprio(0);                                               \
} while (0)

// Fused GEMM (M=87296, N=1024, K=640) + bias + GLU epilogue.
// 256x256 tile, BK=32, 8 waves (2M x 4N), 128 KiB LDS as FOUR rotating slots
// (tile t in slot t&3, prefetch depth 3 -> staging hits slot (t-1)&3, whose
// last LDS read finished before the end-of-(t-1) barrier -> race-free).
// KEY CHANGE vs previous round: register-level fragment PING-PONG. Tile t's
// fragments are read from LDS during tile t-1 and consumed from registers,
// so each tile issues its ds_reads (for t+1) and then MFMAs (for t) with NO
// intra-tile barrier -- the LDS pipe drains under the MFMA clusters instead
// of alternating with them in lockstep. One barrier + counted vmcnt(4) per
// tile boundary is the only block-wide sync (guarantees tiles <= t+2 landed).
// lgkmcnt(8) per tile (FIFO: all but the 8 just-issued reads done) covers
// the consumed set's completion.
__global__ __launch_bounds__(512, 2)
void glu_gemm(const __bf16* __restrict__ A,
              const __bf16* __restrict__ Wb,
              const float* __restrict__ bias,
              float* __restrict__ out) {
    __shared__ __bf16 lds[4 * SLOT];   // 128 KiB

    const int tid  = threadIdx.x;
    const int lane = tid & 63;
    const int w    = tid >> 6;        // wave 0..7
    const int wm   = w >> 2;          // 0..1 (M half)
    const int wn   = w & 3;           // 0..3 (N quarter)

    // XCD-aware swizzle: all 4 bn-siblings of one bm share bid%8 -> same XCD L2.
    const int bid = blockIdx.x;
    const int bn  = (bid >> 3) & 3;
    const int bm  = (bid >> 5) * 8 + (bid & 7);
    if (bm >= MBLK) return;           // 12 idle tail blocks (341 padded to 344); block-uniform

    // ---- staging lane constants (unchanged, verified) ----
    const int sl  = lane >> 3;
    const int sp  = lane & 7;
    const int sc  = sp ^ sl;          // logical c' = (row-parity)*4 + chunk
    const int scc = (sc & 3) * 8;     // k element offset within 32-wide tile
    const int srp = sc >> 2;          // row parity
    int aG[2], bG[2];
#pragma unroll
    for (int h = 0; h < 2; ++h) {
        int R = 2 * (h * 64 + w * 8 + sl) + srp;   // row within 256-row tile
        int m = bm * 256 + R;
        aG[h] = (m & 31) * SRC_STRIDE + (m >> 5) * 240 + scc;
        int n = bn * 256 + R;
        bG[h] = n * 640 + scc;
    }
    const int aD0 = (w * 8) * 64;          // LDS dest bases (elements, wave-uniform)
    const int aD1 = (64 + w * 8) * 64;
    const int bD0 = 8192 + aD0;
    const int bD1 = 8192 + aD1;

    // ---- fragment read constants (unchanged, verified) ----
    const int ll  = (lane & 15) >> 1;
    const int pfr = (((lane & 1) << 2) | (lane >> 4)) ^ ll;
    const int aB  = (wm * 64 + ll) * 64 + pfr * 8;          // elements
    const int bB  = 8192 + (wn * 32 + ll) * 64 + pfr * 8;   // elements

    const unsigned LB    = (unsigned)(unsigned long long)(&lds[0]);
    const unsigned adrA0 = LB + 2u * (unsigned)aB;
    const unsigned adrB0 = LB + 2u * (unsigned)bB;

    f32x4 acc[8][4] = {};
    bf16x8 aE0, aE1, aE2, aE3, aE4, aE5, aE6, aE7, bE0, bE1, bE2, bE3;
    bf16x8 aO0, aO1, aO2, aO3, aO4, aO5, aO6, aO7, bO0, bO1, bO2, bO3;

    // ---- prologue: stage tiles 0,1,2; wait tiles 0,1; read tile-0 frags -> set E ----
    STAGE_T(0); STAGE_T(1); STAGE_T(2);
    asm volatile("s_waitcnt vmcnt(4)" ::: "memory");   // tiles 0,1 landed; 2 in flight
    __builtin_amdgcn_s_barrier();
    __builtin_amdgcn_sched_barrier(0);
    {
        const unsigned sa_ = adrA0;                     // slot 0
        const unsigned sb_ = adrB0;
        READ_B4_A4(E, sa_, sb_)
        READ_A4HI(E, sa_)
    }

    // ---- main loop: tiles 0..17 (2 per iteration), boundary = vmcnt + 1 barrier ----
#pragma unroll 1
    for (int i = 0; i < 9; ++i) {
        const int t = 2 * i;
        TILE(E, O, t, 1);
        asm volatile("s_waitcnt vmcnt(4)" ::: "memory");
        __builtin_amdgcn_s_barrier();
        __builtin_amdgcn_sched_barrier(0);
        TILE(O, E, t + 1, (i < 8));
        if (i < 8) asm volatile("s_waitcnt vmcnt(4)" ::: "memory");
        else       asm volatile("s_waitcnt vmcnt(0)" ::: "memory");
        __builtin_amdgcn_s_barrier();
        __builtin_amdgcn_sched_barrier(0);
    }
    // ---- peeled tail: tile 18 (reads tile 19 frags), tile 19 (registers only) ----
    TILE(E, O, 18, 0);
    asm volatile("s_waitcnt lgkmcnt(0)" ::: "memory");
    __builtin_amdgcn_sched_barrier(0);
    __builtin_amdgcn_s_setprio(1);
    MFMA_LO(O)
    MFMA_HI(O)
    __builtin_amdgcn_s_setprio(0);

    // ---- epilogue: bias + GLU (value frag 2i pairs with gate frag 2i+1; same lane/reg) ----
    const int col = lane & 15;
    const int q   = lane >> 4;
    float bvs[4];
#pragma unroll
    for (int nf = 0; nf < 4; ++nf)
        bvs[nf] = bias[bn * 256 + wn * 64 + nf * 16 + col];

    const int tb = bm * 8 + wm * 4;
#pragma unroll
    for (int i = 0; i < 4; ++i) {
        const int t = tb + i;
#pragma unroll
        for (int nf = 0; nf < 4; ++nf) {
            const int n = bn * 256 + wn * 64 + nf * 16 + col;
#pragma unroll
            for (int r2 = 0; r2 < 4; ++r2) {
                const int brow = q * 4 + r2;           // b in 0..15 (value rows)
                float v = acc[2 * i][nf][r2] + bvs[nf];
                float g = acc[2 * i + 1][nf][r2] + bvs[nf];
                float s = 1.0f / (1.0f + __expf(-g));
                out[((long)(t * 16 + brow)) * 1024 + n] = v * s;
            }
        }
    }
}

extern "C" void kernel_launch(void* const* d_in, const int* in_sizes, int n_in,
                              void* d_out, int out_size, void* d_ws, size_t ws_size,
                              hipStream_t stream) {
    const float* src  = (const float*)d_in[0];
    const int*   lens = (const int*)d_in[1];
    const float* Wf   = (const float*)d_in[2];
    const float* bias = (const float*)d_in[3];
    float* out = (float*)d_out;

    unsigned short* srcb = (unsigned short*)d_ws;          // 20971520 bf16 = 41.9 MB
    unsigned short* wb   = srcb + SRC_ELEMS;               // 655360 bf16 = 1.3 MB

    // bf16 pre-pass (src + W)
    cvt_kernel<<<SRC_ELEMS / 4 / 256, 256, 0, stream>>>(src, srcb, SRC_ELEMS / 4);
    cvt_kernel<<<W_ELEMS / 4 / 256, 256, 0, stream>>>(Wf, wb, W_ELEMS / 4);

    // out_lengths
    lengths_kernel<<<1, 64, 0, stream>>>(lens, out);

    // fused GEMM + GLU: 43 groups x (4 bn x 8 bm_local) = 1376 blocks (12 idle tail)
    glu_gemm<<<43 * 32, 512, 0, stream>>>((const __bf16*)srcb, (const __bf16*)wb, bias, out);
}